// Round 3
// baseline (197148.901 us; speedup 1.0000x reference)
//
#include <hip/hip_runtime.h>
#include <cmath>

#define DD 1024
#define TT 200
#define NWG 256
#define GRP 32   // WGs per btile group (independent barrier domain)
#define THR 512

typedef __attribute__((ext_vector_type(4))) float f32x4;

__device__ __forceinline__ float eluf(float x) { return x > 0.f ? x : expm1f(x); }

// Coherent (cross-XCD) scalar store: write-through to MALL, no L2 allocation.
// Activations use this so NO cache-flush fences are ever needed -> each XCD's
// L2 keeps its weight slices resident for the whole kernel.
__device__ __forceinline__ void store_coh(float* p, float v) {
  asm volatile("global_store_dword %0, %1, off sc0 sc1" :: "v"(p), "v"(v) : "memory");
}

// ---------------- 1024x1024 transpose: dst[k][n] = src[n][k] ----------------
__global__ __launch_bounds__(256) void transpose_k(const float* __restrict__ src,
                                                   float* __restrict__ dst) {
  __shared__ float tile[32][33];
  const int bx = blockIdx.x << 5;
  const int by = blockIdx.y << 5;
  const int tx = threadIdx.x & 31;
  const int ty = threadIdx.x >> 5;
#pragma unroll
  for (int i = 0; i < 4; ++i) {
    int r = ty + (i << 3);
    tile[r][tx] = src[(size_t)(bx + r) * DD + by + tx];
  }
  __syncthreads();
#pragma unroll
  for (int i = 0; i < 4; ++i) {
    int r = ty + (i << 3);
    dst[(size_t)(by + r) * DD + bx + tx] = tile[tx][r];
  }
}

// ---------------- phase 0: wxT[b][n][t] = sum_k x[b][k][t]*Win[n][k] + bin[n]
__global__ __launch_bounds__(256) void wx_kernel(const float* __restrict__ x,
                                                 const float* __restrict__ Win,
                                                 const float* __restrict__ bin,
                                                 float* __restrict__ wxT) {
  const int gw = (blockIdx.x << 2) | (threadIdx.x >> 6);
  const int lane = threadIdx.x & 63;
  const int noct = gw & 127;
  const int tt = (gw >> 7) & 3;
  const int b = gw >> 9;
  const int n0 = noct << 3;
  const int t = (tt << 6) + lane;
  const int tl = t < TT ? t : (TT - 1);
  const float* xp = x + (size_t)b * DD * TT + tl;
  float acc[8];
#pragma unroll
  for (int j = 0; j < 8; ++j) acc[j] = 0.f;
  for (int k = 0; k < DD; k += 4) {
    float x0 = xp[(size_t)(k + 0) * TT];
    float x1 = xp[(size_t)(k + 1) * TT];
    float x2 = xp[(size_t)(k + 2) * TT];
    float x3 = xp[(size_t)(k + 3) * TT];
#pragma unroll
    for (int j = 0; j < 8; ++j) {
      const float4 w = *(const float4*)(Win + (size_t)(n0 + j) * DD + k);
      acc[j] = fmaf(x0, w.x, fmaf(x1, w.y, fmaf(x2, w.z, fmaf(x3, w.w, acc[j]))));
    }
  }
  if (t < TT) {
#pragma unroll
    for (int j = 0; j < 8; ++j)
      wxT[((size_t)b * DD + n0 + j) * TT + t] = acc[j] + bin[n0 + j];
  }
}

// -------- per-btile-group barrier: monotonic, reset-free, fence-free --------
// All cross-WG dataflow is within a 32-WG btile group (rows 8b..8b+7), so each
// group syncs only among itself: 32 arrivals on its own 128B line. Monotonic
// counter -> no reset race. No cache fences anywhere: activations are sc0/sc1
// (coherence point = MALL); visibility ordering is each wave's own
// s_waitcnt vmcnt(0) (sc1 store retirement == visible at MALL) before
// s_barrier, then one arrival RMW per WG, executed at MALL after the drain.
__device__ __forceinline__ void group_barrier(unsigned* cnt, unsigned target) {
  asm volatile("s_waitcnt vmcnt(0)" ::: "memory");  // this wave's stores @ MALL
  __syncthreads();                                   // whole WG drained
  if (threadIdx.x == 0) {
    __hip_atomic_fetch_add(cnt, 1u, __ATOMIC_RELAXED, __HIP_MEMORY_SCOPE_AGENT);
    while (__hip_atomic_load(cnt, __ATOMIC_RELAXED, __HIP_MEMORY_SCOPE_AGENT) < target)
      __builtin_amdgcn_s_sleep(2);  // backoff: cut MALL contention on the line
  }
  __syncthreads();
}

// ---------------- one GEMM stage: out[b0+r][n] = sum_k in[b0+r][k]*Wt[k][n]
// WG: 512 thr = 8 waves. Tile 8 b-rows x 32 n-cols. Wave = k-eighth (128).
// Thread: 1 n-col (nl), 4 b-rows (half-wave bg). Weights 8-deep double-buffered.
// Staging loads: 4x dwordx4 sc0+sc1 (MALL-coherent, 64B/thread in flight).
// Weight loads: normal cached -> warm XCD L2 every window (never invalidated).
__device__ __forceinline__ float stage_gemm(const float* __restrict__ Wt,
                                            const float* __restrict__ inrows,
                                            float* __restrict__ in_s,
                                            float* __restrict__ red,
                                            int tid, int k0, int nn, int bg) {
  {  // stage 8 rows (32 KB) into LDS: 4 float4 per thread, coalesced
    const f32x4* __restrict__ s4 = (const f32x4*)inrows;
    f32x4* d4 = (f32x4*)in_s;
    f32x4 t0, t1, t2, t3;
    asm volatile(
        "global_load_dwordx4 %0, %4, off sc0 sc1\n\t"
        "global_load_dwordx4 %1, %5, off sc0 sc1\n\t"
        "global_load_dwordx4 %2, %6, off sc0 sc1\n\t"
        "global_load_dwordx4 %3, %7, off sc0 sc1\n\t"
        "s_waitcnt vmcnt(0)"
        : "=&v"(t0), "=&v"(t1), "=&v"(t2), "=&v"(t3)
        : "v"(s4 + tid), "v"(s4 + tid + 512), "v"(s4 + tid + 1024), "v"(s4 + tid + 1536)
        : "memory");
    d4[tid] = t0;
    d4[tid + 512] = t1;
    d4[tid + 1024] = t2;
    d4[tid + 1536] = t3;
  }
  __syncthreads();

  const float* wp = Wt + (size_t)k0 * DD + nn;  // lane-coalesced over n
  const float* isp = in_s + ((bg << 2) << 10) + k0;
  float acc[4];
#pragma unroll
  for (int j = 0; j < 4; ++j) acc[j] = 0.f;
  float wa[8], wb[8];
#pragma unroll
  for (int j = 0; j < 8; ++j) wa[j] = wp[j * DD];

#pragma unroll
  for (int kk = 0; kk < 128; kk += 16) {
#pragma unroll
    for (int j = 0; j < 8; ++j) wb[j] = wp[(kk + 8 + j) * DD];
#pragma unroll
    for (int rr = 0; rr < 4; ++rr) {
      const float4 a = *(const float4*)(isp + (rr << 10) + kk);  // LDS bcast/half-wave
      const float4 b = *(const float4*)(isp + (rr << 10) + kk + 4);
      acc[rr] = fmaf(a.x, wa[0], fmaf(a.y, wa[1], fmaf(a.z, wa[2], fmaf(a.w, wa[3], acc[rr]))));
      acc[rr] = fmaf(b.x, wa[4], fmaf(b.y, wa[5], fmaf(b.z, wa[6], fmaf(b.w, wa[7], acc[rr]))));
    }
#pragma unroll
    for (int j = 0; j < 8; ++j) wa[j] = wp[((kk + 16 + j) & 127) * DD];  // wrap: in-bounds
#pragma unroll
    for (int rr = 0; rr < 4; ++rr) {
      const float4 a = *(const float4*)(isp + (rr << 10) + kk + 8);
      const float4 b = *(const float4*)(isp + (rr << 10) + kk + 12);
      acc[rr] = fmaf(a.x, wb[0], fmaf(a.y, wb[1], fmaf(a.z, wb[2], fmaf(a.w, wb[3], acc[rr]))));
      acc[rr] = fmaf(b.x, wb[4], fmaf(b.y, wb[5], fmaf(b.z, wb[6], fmaf(b.w, wb[7], acc[rr]))));
    }
  }

  // cross-wave K reduction through LDS
  const int ob = ((tid >> 6) << 8) + (bg << 7) + (nn & 31);
  red[ob] = acc[0];
  red[ob + 32] = acc[1];
  red[ob + 64] = acc[2];
  red[ob + 96] = acc[3];
  __syncthreads();
  float v = 0.f;
  if (tid < 256) {
#pragma unroll
    for (int w = 0; w < 8; ++w) v += red[(w << 8) + tid];
  }
  return v;
}

// ---------------- the whole sequential scan, one cooperative kernel --------
__global__ void __launch_bounds__(THR, 1) rnn_kernel(
    const float* __restrict__ WtH, const float* __restrict__ Wt2,
    const float* __restrict__ Wt3, const float* __restrict__ WtO,
    const float* __restrict__ bh_, const float* __restrict__ b2_,
    const float* __restrict__ b3_, const float* __restrict__ bo_,
    const float* __restrict__ etas_, const float* __restrict__ wxT,
    float* __restrict__ sbuf, float* __restrict__ F1b, float* __restrict__ Gb,
    float* __restrict__ hb, float* __restrict__ outp,
    unsigned* __restrict__ bar) {
  __shared__ float in_s[8192];  // 32 KB
  __shared__ float red[2048];   // 8 KB
  const int tid = threadIdx.x;
  const int lane = tid & 63;
  const int ntile = blockIdx.x & 31;  // blk%8 -> XCD: weight slices L2/IF$-local
  const int btile = blockIdx.x >> 5;
  const int n0 = ntile << 5;
  const int b0 = btile << 3;
  const int nl = lane & 31;
  const int bg = lane >> 5;
  const int nn = n0 + nl;
  const int k0 = (tid >> 6) << 7;  // wave's 128-k slice

  unsigned* gcnt = bar + (btile << 5);  // this group's 128B arrival line

  const bool owner = tid < 256;  // threads that own one output element
  const int orow = (tid & 255) >> 5;
  const int ocol = tid & 31;
  const size_t o = (size_t)(b0 + orow) * DD + (n0 + ocol);

  const float bh = bh_[n0 + ocol], bb2 = b2_[n0 + ocol];
  const float bb3 = b3_[n0 + ocol], bo = bo_[n0 + ocol];
  float eta[5];
#pragma unroll
  for (int i = 0; i < 5; ++i) eta[i] = etas_[i];

  const float* in_sb = sbuf + (size_t)b0 * DD;
  const float* in_F = F1b + (size_t)b0 * DD;
  const float* in_G = Gb + (size_t)b0 * DD;
  const float* in_h = hb + (size_t)b0 * DD;
  const float* wxp = wxT + o * TT;

  float h = 0.f, h0 = 0.f;  // private h-element (owner threads only)
  unsigned g = 0;
  for (int t = 0; t < TT; ++t) {
    for (int it = 0; it < 5; ++it) {
      if (it == 0 && t > 0) {
        // output GEMM for previous step shares this barrier window with stage A
        float v = stage_gemm(WtO, in_h, in_s, red, tid, k0, nn, bg);
        if (owner) outp[o * TT + (t - 1)] = v + bo;
      }
      // stage A: F1 = elu((h+h0)@Whid^T + bh + wx)
      float v = stage_gemm(WtH, in_sb, in_s, red, tid, k0, nn, bg);
      if (owner) store_coh(F1b + o, eluf(v + bh + wxp[t]));
      group_barrier(gcnt, (++g) * GRP);
      // stage B: G = elu(F1@W2^T + b2)
      v = stage_gemm(Wt2, in_F, in_s, red, tid, k0, nn, bg);
      if (owner) store_coh(Gb + o, eluf(v + bb2));
      group_barrier(gcnt, (++g) * GRP);
      // stage C: Fn = elu(G@W3^T + b3); h += eta*(Fn - h - h0)
      v = stage_gemm(Wt3, in_G, in_s, red, tid, k0, nn, bg);
      if (owner) {
        float fn = eluf(v + bb3);
        float e = eta[it];
        h += e * (fn - h - h0);
        if (it == 4) {  // step transition: h0 <- h_t, s <- 2*h_t
          h0 = h;
          store_coh(sbuf + o, 2.f * h);
          store_coh(hb + o, h);  // consumed by next window's output GEMM
        } else {
          store_coh(sbuf + o, h + h0);
        }
      }
      group_barrier(gcnt, (++g) * GRP);
    }
  }
  float v = stage_gemm(WtO, in_h, in_s, red, tid, k0, nn, bg);
  if (owner) outp[o * TT + (TT - 1)] = v + bo;
}

extern "C" void kernel_launch(void* const* d_in, const int* in_sizes, int n_in,
                              void* d_out, int out_size, void* d_ws, size_t ws_size,
                              hipStream_t stream) {
  const float* x = (const float*)d_in[0];
  const float* Win = (const float*)d_in[1];
  const float* bin = (const float*)d_in[2];
  const float* Whid = (const float*)d_in[3];
  const float* bhid = (const float*)d_in[4];
  const float* W2 = (const float*)d_in[5];
  const float* b2 = (const float*)d_in[6];
  const float* W3 = (const float*)d_in[7];
  const float* b3 = (const float*)d_in[8];
  const float* Wout = (const float*)d_in[9];
  const float* bout = (const float*)d_in[10];
  const float* etas = (const float*)d_in[11];
  float* out = (float*)d_out;

  char* ws = (char*)d_ws;
  float* wxT = (float*)(ws);                   // 52.4 MB  [B][D][T]
  float* WtH = (float*)(ws + 52428800);        // 4 MB each, k-major
  float* Wt2 = (float*)(ws + 56623104);
  float* Wt3 = (float*)(ws + 60817408);
  float* WtO = (float*)(ws + 65011712);
  float* sbuf = (float*)(ws + 69206016);       // 256 KB each
  float* F1b = (float*)(ws + 69468160);
  float* Gb = (float*)(ws + 69730304);
  float* hb = (float*)(ws + 69992448);
  unsigned* bar = (unsigned*)(ws + 70516736);  // 8 group counters, 128B apart

  hipMemsetAsync(sbuf, 0, 262144, stream);
  hipMemsetAsync(bar, 0, 4096, stream);

  dim3 tb(256);
  dim3 tg(32, 32);
  hipLaunchKernelGGL(transpose_k, tg, tb, 0, stream, Whid, WtH);
  hipLaunchKernelGGL(transpose_k, tg, tb, 0, stream, W2, Wt2);
  hipLaunchKernelGGL(transpose_k, tg, tb, 0, stream, W3, Wt3);
  hipLaunchKernelGGL(transpose_k, tg, tb, 0, stream, Wout, WtO);
  hipLaunchKernelGGL(wx_kernel, dim3(8192), tb, 0, stream, x, Win, bin, wxT);

  void* args[] = {&WtH, &Wt2, &Wt3, &WtO, &bhid, &b2, &b3, &bout, &etas,
                  &wxT, &sbuf, &F1b, &Gb, &hb, &out, &bar};
  hipLaunchCooperativeKernel((void*)rnn_kernel, dim3(NWG), dim3(THR), args, 0, stream);
}

// Round 6
// 90121.552 us; speedup vs baseline: 2.1876x; 2.1876x over previous
//
#include <hip/hip_runtime.h>
#include <cmath>

#define DD 1024
#define TT 200
#define NWG 256
#define THR 512

__device__ __forceinline__ float eluf(float x) { return x > 0.f ? x : expm1f(x); }

// ---------------- 1024x1024 transpose: dst[k][n] = src[n][k] ----------------
__global__ __launch_bounds__(256) void transpose_k(const float* __restrict__ src,
                                                   float* __restrict__ dst) {
  __shared__ float tile[32][33];
  const int bx = blockIdx.x << 5;
  const int by = blockIdx.y << 5;
  const int tx = threadIdx.x & 31;
  const int ty = threadIdx.x >> 5;
#pragma unroll
  for (int i = 0; i < 4; ++i) {
    int r = ty + (i << 3);
    tile[r][tx] = src[(size_t)(bx + r) * DD + by + tx];
  }
  __syncthreads();
#pragma unroll
  for (int i = 0; i < 4; ++i) {
    int r = ty + (i << 3);
    dst[(size_t)(by + r) * DD + bx + tx] = tile[tx][r];
  }
}

// ---------------- phase 0: wxT[b][n][t] = sum_k x[b][k][t]*Win[n][k] + bin[n]
__global__ __launch_bounds__(256) void wx_kernel(const float* __restrict__ x,
                                                 const float* __restrict__ Win,
                                                 const float* __restrict__ bin,
                                                 float* __restrict__ wxT) {
  const int gw = (blockIdx.x << 2) | (threadIdx.x >> 6);
  const int lane = threadIdx.x & 63;
  const int noct = gw & 127;
  const int tt = (gw >> 7) & 3;
  const int b = gw >> 9;
  const int n0 = noct << 3;
  const int t = (tt << 6) + lane;
  const int tl = t < TT ? t : (TT - 1);
  const float* xp = x + (size_t)b * DD * TT + tl;
  float acc[8];
#pragma unroll
  for (int j = 0; j < 8; ++j) acc[j] = 0.f;
  for (int k = 0; k < DD; k += 4) {
    float x0 = xp[(size_t)(k + 0) * TT];
    float x1 = xp[(size_t)(k + 1) * TT];
    float x2 = xp[(size_t)(k + 2) * TT];
    float x3 = xp[(size_t)(k + 3) * TT];
#pragma unroll
    for (int j = 0; j < 8; ++j) {
      const float4 w = *(const float4*)(Win + (size_t)(n0 + j) * DD + k);
      acc[j] = fmaf(x0, w.x, fmaf(x1, w.y, fmaf(x2, w.z, fmaf(x3, w.w, acc[j]))));
    }
  }
  if (t < TT) {
#pragma unroll
    for (int j = 0; j < 8; ++j)
      wxT[((size_t)b * DD + n0 + j) * TT + t] = acc[j] + bin[n0 + j];
  }
}

// ------- two-level generation barrier (R0 fence protocol, tree arrival) -----
// Monotonic counters, no resets. Level 1: 8 group lines (one per btile, 128B
// apart), 32 RMWs each, MALL serves lines in parallel. The 32nd arriver of a
// group (old == 32*g-1) delegates one RMW to the root line (8/barrier),
// delegates spin on root, then release-publish their group's gen word; the
// other 31 members spin on their own group's gen line. Fence placement is
// identical to the round-0 verified protocol: release threadfence (wbl2)
// before arrival, acquire threadfence (inv) after the generation observed.
__device__ __forceinline__ void grid_barrier(unsigned* bar, int grp, unsigned g1) {
  __syncthreads();
  if (threadIdx.x == 0) {
    __threadfence();  // release: write back dirty L2 (activations) to MALL
    unsigned* gcnt = bar + 32 + (grp << 5);   // this group's arrival line
    unsigned* ggen = bar + 512 + (grp << 5);  // this group's generation line
    unsigned old = __hip_atomic_fetch_add(gcnt, 1u, __ATOMIC_ACQ_REL, __HIP_MEMORY_SCOPE_AGENT);
    if (old == (g1 << 5) - 1) {  // delegate: whole group has arrived
      unsigned r = __hip_atomic_fetch_add(bar, 1u, __ATOMIC_ACQ_REL, __HIP_MEMORY_SCOPE_AGENT);
      if (r != (g1 << 3) - 1) {  // not the globally-last delegate: wait for root
        while (__hip_atomic_load(bar, __ATOMIC_RELAXED, __HIP_MEMORY_SCOPE_AGENT) < (g1 << 3))
          __builtin_amdgcn_s_sleep(1);
      }
      __hip_atomic_store(ggen, g1, __ATOMIC_RELEASE, __HIP_MEMORY_SCOPE_AGENT);
    } else {
      while (__hip_atomic_load(ggen, __ATOMIC_RELAXED, __HIP_MEMORY_SCOPE_AGENT) < g1)
        __builtin_amdgcn_s_sleep(1);
    }
    __threadfence();  // acquire: invalidate CU L0 + XCD L2 before reading peers' data
  }
  __syncthreads();
}

// ---------------- one GEMM stage: out[b0+r][n] = sum_k in[b0+r][k]*Wt[k][n]
// WG: 512 thr = 8 waves. Tile 8 b-rows x 32 n-cols. Wave = k-eighth (128).
// Thread: 1 n-col (nl), 4 b-rows (half-wave bg). Weights 8-deep double-buffered.
__device__ __forceinline__ float stage_gemm(const float* __restrict__ Wt,
                                            const float* __restrict__ inrows,
                                            float* __restrict__ in_s,
                                            float* __restrict__ red,
                                            int tid, int k0, int nn, int bg) {
  {  // stage 8 rows (32 KB) into LDS: 4 float4 per thread, coalesced
    const float4* __restrict__ s4 = (const float4*)inrows;
    float4* d4 = (float4*)in_s;
    float4 t0 = s4[tid], t1 = s4[tid + 512], t2 = s4[tid + 1024], t3 = s4[tid + 1536];
    d4[tid] = t0;
    d4[tid + 512] = t1;
    d4[tid + 1024] = t2;
    d4[tid + 1536] = t3;
  }
  __syncthreads();

  const float* wp = Wt + (size_t)k0 * DD + nn;  // lane-coalesced over n
  const float* isp = in_s + ((bg << 2) << 10) + k0;
  float acc[4];
#pragma unroll
  for (int j = 0; j < 4; ++j) acc[j] = 0.f;
  float wa[8], wb[8];
#pragma unroll
  for (int j = 0; j < 8; ++j) wa[j] = wp[j * DD];

#pragma unroll
  for (int kk = 0; kk < 128; kk += 16) {
#pragma unroll
    for (int j = 0; j < 8; ++j) wb[j] = wp[(kk + 8 + j) * DD];
#pragma unroll
    for (int rr = 0; rr < 4; ++rr) {
      const float4 a = *(const float4*)(isp + (rr << 10) + kk);  // LDS bcast/half-wave
      const float4 b = *(const float4*)(isp + (rr << 10) + kk + 4);
      acc[rr] = fmaf(a.x, wa[0], fmaf(a.y, wa[1], fmaf(a.z, wa[2], fmaf(a.w, wa[3], acc[rr]))));
      acc[rr] = fmaf(b.x, wa[4], fmaf(b.y, wa[5], fmaf(b.z, wa[6], fmaf(b.w, wa[7], acc[rr]))));
    }
#pragma unroll
    for (int j = 0; j < 8; ++j) wa[j] = wp[((kk + 16 + j) & 127) * DD];  // wrap: in-bounds
#pragma unroll
    for (int rr = 0; rr < 4; ++rr) {
      const float4 a = *(const float4*)(isp + (rr << 10) + kk + 8);
      const float4 b = *(const float4*)(isp + (rr << 10) + kk + 12);
      acc[rr] = fmaf(a.x, wb[0], fmaf(a.y, wb[1], fmaf(a.z, wb[2], fmaf(a.w, wb[3], acc[rr]))));
      acc[rr] = fmaf(b.x, wb[4], fmaf(b.y, wb[5], fmaf(b.z, wb[6], fmaf(b.w, wb[7], acc[rr]))));
    }
  }

  // cross-wave K reduction through LDS
  const int ob = ((tid >> 6) << 8) + (bg << 7) + (nn & 31);
  red[ob] = acc[0];
  red[ob + 32] = acc[1];
  red[ob + 64] = acc[2];
  red[ob + 96] = acc[3];
  __syncthreads();
  float v = 0.f;
  if (tid < 256) {
#pragma unroll
    for (int w = 0; w < 8; ++w) v += red[(w << 8) + tid];
  }
  return v;
}

// ---------------- the whole sequential scan, one cooperative kernel --------
__global__ void __launch_bounds__(THR, 1) rnn_kernel(
    const float* __restrict__ WtH, const float* __restrict__ Wt2,
    const float* __restrict__ Wt3, const float* __restrict__ WtO,
    const float* __restrict__ bh_, const float* __restrict__ b2_,
    const float* __restrict__ b3_, const float* __restrict__ bo_,
    const float* __restrict__ etas_, const float* __restrict__ wxT,
    float* __restrict__ sbuf, float* __restrict__ F1b, float* __restrict__ Gb,
    float* __restrict__ hb, float* __restrict__ outp,
    unsigned* __restrict__ bar) {
  __shared__ float in_s[8192];  // 32 KB
  __shared__ float red[2048];   // 8 KB
  const int tid = threadIdx.x;
  const int lane = tid & 63;
  const int ntile = blockIdx.x & 31;  // blk%8 -> XCD: weight slices L2/IF$-local
  const int btile = blockIdx.x >> 5;
  const int n0 = ntile << 5;
  const int b0 = btile << 3;
  const int nl = lane & 31;
  const int bg = lane >> 5;
  const int nn = n0 + nl;
  const int k0 = (tid >> 6) << 7;  // wave's 128-k slice

  const bool owner = tid < 256;  // threads that own one output element
  const int orow = (tid & 255) >> 5;
  const int ocol = tid & 31;
  const size_t o = (size_t)(b0 + orow) * DD + (n0 + ocol);

  const float bh = bh_[n0 + ocol], bb2 = b2_[n0 + ocol];
  const float bb3 = b3_[n0 + ocol], bo = bo_[n0 + ocol];
  float eta[5];
#pragma unroll
  for (int i = 0; i < 5; ++i) eta[i] = etas_[i];

  const float* in_sb = sbuf + (size_t)b0 * DD;
  const float* in_F = F1b + (size_t)b0 * DD;
  const float* in_G = Gb + (size_t)b0 * DD;
  const float* in_h = hb + (size_t)b0 * DD;
  const float* wxp = wxT + o * TT;

  float h = 0.f, h0 = 0.f;  // private h-element (owner threads only)
  unsigned g = 0;
  for (int t = 0; t < TT; ++t) {
    for (int it = 0; it < 5; ++it) {
      if (it == 0 && t > 0) {
        // output GEMM for previous step shares this barrier window with stage A
        float v = stage_gemm(WtO, in_h, in_s, red, tid, k0, nn, bg);
        if (owner) outp[o * TT + (t - 1)] = v + bo;
      }
      // stage A: F1 = elu((h+h0)@Whid^T + bh + wx)
      float v = stage_gemm(WtH, in_sb, in_s, red, tid, k0, nn, bg);
      if (owner) F1b[o] = eluf(v + bh + wxp[t]);
      grid_barrier(bar, btile, ++g);
      // stage B: G = elu(F1@W2^T + b2)
      v = stage_gemm(Wt2, in_F, in_s, red, tid, k0, nn, bg);
      if (owner) Gb[o] = eluf(v + bb2);
      grid_barrier(bar, btile, ++g);
      // stage C: Fn = elu(G@W3^T + b3); h += eta*(Fn - h - h0)
      v = stage_gemm(Wt3, in_G, in_s, red, tid, k0, nn, bg);
      if (owner) {
        float fn = eluf(v + bb3);
        float e = eta[it];
        h += e * (fn - h - h0);
        if (it == 4) {  // step transition: h0 <- h_t, s <- 2*h_t
          h0 = h;
          sbuf[o] = 2.f * h;
          hb[o] = h;  // consumed by next window's output GEMM
        } else {
          sbuf[o] = h + h0;
        }
      }
      grid_barrier(bar, btile, ++g);
    }
  }
  float v = stage_gemm(WtO, in_h, in_s, red, tid, k0, nn, bg);
  if (owner) outp[o * TT + (TT - 1)] = v + bo;
}

extern "C" void kernel_launch(void* const* d_in, const int* in_sizes, int n_in,
                              void* d_out, int out_size, void* d_ws, size_t ws_size,
                              hipStream_t stream) {
  const float* x = (const float*)d_in[0];
  const float* Win = (const float*)d_in[1];
  const float* bin = (const float*)d_in[2];
  const float* Whid = (const float*)d_in[3];
  const float* bhid = (const float*)d_in[4];
  const float* W2 = (const float*)d_in[5];
  const float* b2 = (const float*)d_in[6];
  const float* W3 = (const float*)d_in[7];
  const float* b3 = (const float*)d_in[8];
  const float* Wout = (const float*)d_in[9];
  const float* bout = (const float*)d_in[10];
  const float* etas = (const float*)d_in[11];
  float* out = (float*)d_out;

  char* ws = (char*)d_ws;
  float* wxT = (float*)(ws);                   // 52.4 MB  [B][D][T]
  float* WtH = (float*)(ws + 52428800);        // 4 MB each, k-major
  float* Wt2 = (float*)(ws + 56623104);
  float* Wt3 = (float*)(ws + 60817408);
  float* WtO = (float*)(ws + 65011712);
  float* sbuf = (float*)(ws + 69206016);       // 256 KB each
  float* F1b = (float*)(ws + 69468160);
  float* Gb = (float*)(ws + 69730304);
  float* hb = (float*)(ws + 69992448);
  unsigned* bar = (unsigned*)(ws + 70516736);  // root | grp cnt[8] | grp gen[8]

  hipMemsetAsync(sbuf, 0, 262144, stream);
  hipMemsetAsync(bar, 0, 8192, stream);

  dim3 tb(256);
  dim3 tg(32, 32);
  hipLaunchKernelGGL(transpose_k, tg, tb, 0, stream, Whid, WtH);
  hipLaunchKernelGGL(transpose_k, tg, tb, 0, stream, W2, Wt2);
  hipLaunchKernelGGL(transpose_k, tg, tb, 0, stream, W3, Wt3);
  hipLaunchKernelGGL(transpose_k, tg, tb, 0, stream, Wout, WtO);
  hipLaunchKernelGGL(wx_kernel, dim3(8192), tb, 0, stream, x, Win, bin, wxT);

  void* args[] = {&WtH, &Wt2, &Wt3, &WtO, &bhid, &b2, &b3, &bout, &etas,
                  &wxT, &sbuf, &F1b, &Gb, &hb, &out, &bar};
  hipLaunchCooperativeKernel((void*)rnn_kernel, dim3(NWG), dim3(THR), args, 0, stream);
}

// Round 7
// 83837.842 us; speedup vs baseline: 2.3516x; 1.0750x over previous
//
#include <hip/hip_runtime.h>
#include <cmath>

#define DD 1024
#define TT 200
#define NWG 256
#define GRP 32   // WGs per btile group (independent barrier domain)
#define THR 512

__device__ __forceinline__ float eluf(float x) { return x > 0.f ? x : expm1f(x); }

// ---------------- 1024x1024 transpose: dst[k][n] = src[n][k] ----------------
__global__ __launch_bounds__(256) void transpose_k(const float* __restrict__ src,
                                                   float* __restrict__ dst) {
  __shared__ float tile[32][33];
  const int bx = blockIdx.x << 5;
  const int by = blockIdx.y << 5;
  const int tx = threadIdx.x & 31;
  const int ty = threadIdx.x >> 5;
#pragma unroll
  for (int i = 0; i < 4; ++i) {
    int r = ty + (i << 3);
    tile[r][tx] = src[(size_t)(bx + r) * DD + by + tx];
  }
  __syncthreads();
#pragma unroll
  for (int i = 0; i < 4; ++i) {
    int r = ty + (i << 3);
    dst[(size_t)(by + r) * DD + bx + tx] = tile[tx][r];
  }
}

// ---------------- phase 0: wxT[b][n][t] = sum_k x[b][k][t]*Win[n][k] + bin[n]
__global__ __launch_bounds__(256) void wx_kernel(const float* __restrict__ x,
                                                 const float* __restrict__ Win,
                                                 const float* __restrict__ bin,
                                                 float* __restrict__ wxT) {
  const int gw = (blockIdx.x << 2) | (threadIdx.x >> 6);
  const int lane = threadIdx.x & 63;
  const int noct = gw & 127;
  const int tt = (gw >> 7) & 3;
  const int b = gw >> 9;
  const int n0 = noct << 3;
  const int t = (tt << 6) + lane;
  const int tl = t < TT ? t : (TT - 1);
  const float* xp = x + (size_t)b * DD * TT + tl;
  float acc[8];
#pragma unroll
  for (int j = 0; j < 8; ++j) acc[j] = 0.f;
  for (int k = 0; k < DD; k += 4) {
    float x0 = xp[(size_t)(k + 0) * TT];
    float x1 = xp[(size_t)(k + 1) * TT];
    float x2 = xp[(size_t)(k + 2) * TT];
    float x3 = xp[(size_t)(k + 3) * TT];
#pragma unroll
    for (int j = 0; j < 8; ++j) {
      const float4 w = *(const float4*)(Win + (size_t)(n0 + j) * DD + k);
      acc[j] = fmaf(x0, w.x, fmaf(x1, w.y, fmaf(x2, w.z, fmaf(x3, w.w, acc[j]))));
    }
  }
  if (t < TT) {
#pragma unroll
    for (int j = 0; j < 8; ++j)
      wxT[((size_t)b * DD + n0 + j) * TT + t] = acc[j] + bin[n0 + j];
  }
}

// ------- per-btile barrier, R0 fence protocol, monotonic (no reset) --------
// All steady-state dataflow (sbuf/F1b/Gb/hb) is btile-internal, so each group
// of 32 WGs syncs only among itself on its own 128B line. Fence placement is
// byte-identical to the round-0 verified protocol: release threadfence (L2
// writeback) before arrival, acquire threadfence (L1/L2 inv) after the count.
// Weights live in REGISTERS, which buffer_inv does not touch.
__device__ __forceinline__ void group_barrier(unsigned* cnt, unsigned target) {
  __syncthreads();
  if (threadIdx.x == 0) {
    __threadfence();  // release: write back dirty L2 (activations) to MALL
    __hip_atomic_fetch_add(cnt, 1u, __ATOMIC_ACQ_REL, __HIP_MEMORY_SCOPE_AGENT);
    while (__hip_atomic_load(cnt, __ATOMIC_RELAXED, __HIP_MEMORY_SCOPE_AGENT) < target)
      __builtin_amdgcn_s_sleep(1);
    __threadfence();  // acquire: invalidate CU L0 + XCD L2 before reading peers' data
  }
  __syncthreads();
}

// ---- register-weight GEMM stage: out[b0+r][n] = sum_k in[b0+r][k]*W[k][n] --
// Lane (nl,bg) holds W[kbase..kbase+64)[n0+nl] in 64 VGPRs (invalidate-proof).
// acc over all 8 rows; 16 (wave,bg) k-groups reduce through LDS.
__device__ __forceinline__ float reg_gemm(const float (&w)[64],
                                          const float* __restrict__ inrows,
                                          float* __restrict__ in_s,
                                          float* __restrict__ red,
                                          int tid, int kbase, int grp) {
  {  // stage 8 rows (32 KB) into LDS: 4 float4 per thread, coalesced, cached
    const float4* __restrict__ s4 = (const float4*)inrows;
    float4* d4 = (float4*)in_s;
    float4 t0 = s4[tid], t1 = s4[tid + 512], t2 = s4[tid + 1024], t3 = s4[tid + 1536];
    d4[tid] = t0;
    d4[tid + 512] = t1;
    d4[tid + 1024] = t2;
    d4[tid + 1536] = t3;
  }
  __syncthreads();

  float acc[8];
#pragma unroll
  for (int r = 0; r < 8; ++r) acc[r] = 0.f;
  const float* isp = in_s + kbase;
#pragma unroll
  for (int r = 0; r < 8; ++r) {
#pragma unroll
    for (int jj = 0; jj < 16; ++jj) {  // half-wave broadcast reads
      const float4 a = *(const float4*)(isp + (r << 10) + (jj << 2));
      acc[r] = fmaf(a.x, w[4 * jj], fmaf(a.y, w[4 * jj + 1],
                fmaf(a.z, w[4 * jj + 2], fmaf(a.w, w[4 * jj + 3], acc[r]))));
    }
  }

  // 16-group k reduction through LDS: red[grp][row][col]
  float* rp = red + (grp << 8) + (tid & 31);
#pragma unroll
  for (int r = 0; r < 8; ++r) rp[r << 5] = acc[r];
  __syncthreads();
  float v = 0.f;
  if (tid < 256) {
#pragma unroll
    for (int q = 0; q < 16; ++q) v += red[(q << 8) + tid];
  }
  return v;
}

// ---- streamed-weight GEMM (R0 path) — used only for WtO (once per step) ----
__device__ __forceinline__ float stage_gemm(const float* __restrict__ Wt,
                                            const float* __restrict__ inrows,
                                            float* __restrict__ in_s,
                                            float* __restrict__ red,
                                            int tid, int k0, int nn, int bg) {
  {
    const float4* __restrict__ s4 = (const float4*)inrows;
    float4* d4 = (float4*)in_s;
    float4 t0 = s4[tid], t1 = s4[tid + 512], t2 = s4[tid + 1024], t3 = s4[tid + 1536];
    d4[tid] = t0;
    d4[tid + 512] = t1;
    d4[tid + 1024] = t2;
    d4[tid + 1536] = t3;
  }
  __syncthreads();

  const float* wp = Wt + (size_t)k0 * DD + nn;
  const float* isp = in_s + ((bg << 2) << 10) + k0;
  float acc[4];
#pragma unroll
  for (int j = 0; j < 4; ++j) acc[j] = 0.f;
  float wa[8], wb[8];
#pragma unroll
  for (int j = 0; j < 8; ++j) wa[j] = wp[j * DD];

#pragma unroll
  for (int kk = 0; kk < 128; kk += 16) {
#pragma unroll
    for (int j = 0; j < 8; ++j) wb[j] = wp[(kk + 8 + j) * DD];
#pragma unroll
    for (int rr = 0; rr < 4; ++rr) {
      const float4 a = *(const float4*)(isp + (rr << 10) + kk);
      const float4 b = *(const float4*)(isp + (rr << 10) + kk + 4);
      acc[rr] = fmaf(a.x, wa[0], fmaf(a.y, wa[1], fmaf(a.z, wa[2], fmaf(a.w, wa[3], acc[rr]))));
      acc[rr] = fmaf(b.x, wa[4], fmaf(b.y, wa[5], fmaf(b.z, wa[6], fmaf(b.w, wa[7], acc[rr]))));
    }
#pragma unroll
    for (int j = 0; j < 8; ++j) wa[j] = wp[((kk + 16 + j) & 127) * DD];
#pragma unroll
    for (int rr = 0; rr < 4; ++rr) {
      const float4 a = *(const float4*)(isp + (rr << 10) + kk + 8);
      const float4 b = *(const float4*)(isp + (rr << 10) + kk + 12);
      acc[rr] = fmaf(a.x, wb[0], fmaf(a.y, wb[1], fmaf(a.z, wb[2], fmaf(a.w, wb[3], acc[rr]))));
      acc[rr] = fmaf(b.x, wb[4], fmaf(b.y, wb[5], fmaf(b.z, wb[6], fmaf(b.w, wb[7], acc[rr]))));
    }
  }

  const int ob = ((tid >> 6) << 8) + (bg << 7) + (nn & 31);
  red[ob] = acc[0];
  red[ob + 32] = acc[1];
  red[ob + 64] = acc[2];
  red[ob + 96] = acc[3];
  __syncthreads();
  float v = 0.f;
  if (tid < 256) {
#pragma unroll
    for (int w = 0; w < 8; ++w) v += red[(w << 8) + tid];
  }
  return v;
}

// ---------------- the whole sequential scan, one cooperative kernel --------
__global__ void __launch_bounds__(THR, 2) rnn_kernel(
    const float* __restrict__ WtH, const float* __restrict__ Wt2,
    const float* __restrict__ Wt3, const float* __restrict__ WtO,
    const float* __restrict__ bh_, const float* __restrict__ b2_,
    const float* __restrict__ b3_, const float* __restrict__ bo_,
    const float* __restrict__ etas_, const float* __restrict__ wxT,
    float* __restrict__ sbuf, float* __restrict__ F1b, float* __restrict__ Gb,
    float* __restrict__ hb, float* __restrict__ outp,
    unsigned* __restrict__ bar) {
  __shared__ float in_s[8192];  // 32 KB
  __shared__ float red[4096];   // 16 KB (16-group reduce; WtO path uses first 8 KB)
  const int tid = threadIdx.x;
  const int lane = tid & 63;
  const int ntile = blockIdx.x & 31;
  const int btile = blockIdx.x >> 5;
  const int n0 = ntile << 5;
  const int b0 = btile << 3;
  const int nl = lane & 31;
  const int bg = lane >> 5;
  const int nn = n0 + nl;
  const int k0 = (tid >> 6) << 7;   // wave's 128-k slice (WtO path)
  const int grp = tid >> 5;         // 16 (wave,bg) k-groups (reg path)
  const int kbase = grp << 6;       // this lane's 64-k weight window

  unsigned* gcnt = bar + (btile << 5);  // this group's 128B arrival line

  // ---- invalidate-proof weights: 3x64 VGPRs per lane -----------------------
  float whr[64], w2r[64], w3r[64];
  {
    const float* pH = WtH + (size_t)kbase * DD + nn;
    const float* p2 = Wt2 + (size_t)kbase * DD + nn;
    const float* p3 = Wt3 + (size_t)kbase * DD + nn;
#pragma unroll
    for (int j = 0; j < 64; ++j) {
      whr[j] = pH[(size_t)j * DD];
      w2r[j] = p2[(size_t)j * DD];
      w3r[j] = p3[(size_t)j * DD];
    }
  }

  const bool owner = tid < 256;  // threads that own one output element
  const int orow = (tid & 255) >> 5;
  const int ocol = tid & 31;
  const size_t o = (size_t)(b0 + orow) * DD + (n0 + ocol);

  const float bh = bh_[n0 + ocol], bb2 = b2_[n0 + ocol];
  const float bb3 = b3_[n0 + ocol], bo = bo_[n0 + ocol];
  float eta[5];
#pragma unroll
  for (int i = 0; i < 5; ++i) eta[i] = etas_[i];

  const float* in_sb = sbuf + (size_t)b0 * DD;
  const float* in_F = F1b + (size_t)b0 * DD;
  const float* in_G = Gb + (size_t)b0 * DD;
  const float* in_h = hb + (size_t)b0 * DD;
  const float* wxp = wxT + o * TT;

  float h = 0.f, h0 = 0.f;  // private h-element (owner threads only)
  unsigned g = 0;
  for (int t = 0; t < TT; ++t) {
    for (int it = 0; it < 5; ++it) {
      if (it == 0 && t > 0) {
        // output GEMM for previous step shares this barrier window with stage A
        float v = stage_gemm(WtO, in_h, in_s, red, tid, k0, nn, bg);
        if (owner) outp[o * TT + (t - 1)] = v + bo;
      }
      // stage A: F1 = elu((h+h0)@Whid^T + bh + wx)
      const float wxv = wxp[t];  // issue early; cold after inv
      float v = reg_gemm(whr, in_sb, in_s, red, tid, kbase, grp);
      if (owner) F1b[o] = eluf(v + bh + wxv);
      group_barrier(gcnt, (++g) * GRP);
      // stage B: G = elu(F1@W2^T + b2)
      v = reg_gemm(w2r, in_F, in_s, red, tid, kbase, grp);
      if (owner) Gb[o] = eluf(v + bb2);
      group_barrier(gcnt, (++g) * GRP);
      // stage C: Fn = elu(G@W3^T + b3); h += eta*(Fn - h - h0)
      v = reg_gemm(w3r, in_G, in_s, red, tid, kbase, grp);
      if (owner) {
        float fn = eluf(v + bb3);
        float e = eta[it];
        h += e * (fn - h - h0);
        if (it == 4) {  // step transition: h0 <- h_t, s <- 2*h_t
          h0 = h;
          sbuf[o] = 2.f * h;
          hb[o] = h;  // consumed by next window's output GEMM
        } else {
          sbuf[o] = h + h0;
        }
      }
      group_barrier(gcnt, (++g) * GRP);
    }
  }
  float v = stage_gemm(WtO, in_h, in_s, red, tid, k0, nn, bg);
  if (owner) outp[o * TT + (TT - 1)] = v + bo;
}

extern "C" void kernel_launch(void* const* d_in, const int* in_sizes, int n_in,
                              void* d_out, int out_size, void* d_ws, size_t ws_size,
                              hipStream_t stream) {
  const float* x = (const float*)d_in[0];
  const float* Win = (const float*)d_in[1];
  const float* bin = (const float*)d_in[2];
  const float* Whid = (const float*)d_in[3];
  const float* bhid = (const float*)d_in[4];
  const float* W2 = (const float*)d_in[5];
  const float* b2 = (const float*)d_in[6];
  const float* W3 = (const float*)d_in[7];
  const float* b3 = (const float*)d_in[8];
  const float* Wout = (const float*)d_in[9];
  const float* bout = (const float*)d_in[10];
  const float* etas = (const float*)d_in[11];
  float* out = (float*)d_out;

  char* ws = (char*)d_ws;
  float* wxT = (float*)(ws);                   // 52.4 MB  [B][D][T]
  float* WtH = (float*)(ws + 52428800);        // 4 MB each, k-major
  float* Wt2 = (float*)(ws + 56623104);
  float* Wt3 = (float*)(ws + 60817408);
  float* WtO = (float*)(ws + 65011712);
  float* sbuf = (float*)(ws + 69206016);       // 256 KB each
  float* F1b = (float*)(ws + 69468160);
  float* Gb = (float*)(ws + 69730304);
  float* hb = (float*)(ws + 69992448);
  unsigned* bar = (unsigned*)(ws + 70516736);  // 8 group lines, 128B apart

  hipMemsetAsync(sbuf, 0, 262144, stream);
  hipMemsetAsync(bar, 0, 8192, stream);

  dim3 tb(256);
  dim3 tg(32, 32);
  hipLaunchKernelGGL(transpose_k, tg, tb, 0, stream, Whid, WtH);
  hipLaunchKernelGGL(transpose_k, tg, tb, 0, stream, W2, Wt2);
  hipLaunchKernelGGL(transpose_k, tg, tb, 0, stream, W3, Wt3);
  hipLaunchKernelGGL(transpose_k, tg, tb, 0, stream, Wout, WtO);
  hipLaunchKernelGGL(wx_kernel, dim3(8192), tb, 0, stream, x, Win, bin, wxT);

  void* args[] = {&WtH, &Wt2, &Wt3, &WtO, &bhid, &b2, &b3, &bout, &etas,
                  &wxT, &sbuf, &F1b, &Gb, &hb, &out, &bar};
  hipLaunchCooperativeKernel((void*)rnn_kernel, dim3(NWG), dim3(THR), args, 0, stream);
}

// Round 8
// 23426.790 us; speedup vs baseline: 8.4155x; 3.5787x over previous
//
#include <hip/hip_runtime.h>
#include <cmath>

#define DD 1024
#define TT 200
#define NWG 256
#define THR 512

__device__ __forceinline__ float eluf(float x) { return x > 0.f ? x : expm1f(x); }

// ---------------- 1024x1024 transpose: dst[k][n] = src[n][k] ----------------
__global__ __launch_bounds__(256) void transpose_k(const float* __restrict__ src,
                                                   float* __restrict__ dst) {
  __shared__ float tile[32][33];
  const int bx = blockIdx.x << 5;
  const int by = blockIdx.y << 5;
  const int tx = threadIdx.x & 31;
  const int ty = threadIdx.x >> 5;
#pragma unroll
  for (int i = 0; i < 4; ++i) {
    int r = ty + (i << 3);
    tile[r][tx] = src[(size_t)(bx + r) * DD + by + tx];
  }
  __syncthreads();
#pragma unroll
  for (int i = 0; i < 4; ++i) {
    int r = ty + (i << 3);
    dst[(size_t)(by + r) * DD + bx + tx] = tile[tx][r];
  }
}

// ---------------- phase 0: wxT[b][n][t] = sum_k x[b][k][t]*Win[n][k] + bin[n]
__global__ __launch_bounds__(256) void wx_kernel(const float* __restrict__ x,
                                                 const float* __restrict__ Win,
                                                 const float* __restrict__ bin,
                                                 float* __restrict__ wxT) {
  const int gw = (blockIdx.x << 2) | (threadIdx.x >> 6);
  const int lane = threadIdx.x & 63;
  const int noct = gw & 127;
  const int tt = (gw >> 7) & 3;
  const int b = gw >> 9;
  const int n0 = noct << 3;
  const int t = (tt << 6) + lane;
  const int tl = t < TT ? t : (TT - 1);
  const float* xp = x + (size_t)b * DD * TT + tl;
  float acc[8];
#pragma unroll
  for (int j = 0; j < 8; ++j) acc[j] = 0.f;
  for (int k = 0; k < DD; k += 4) {
    float x0 = xp[(size_t)(k + 0) * TT];
    float x1 = xp[(size_t)(k + 1) * TT];
    float x2 = xp[(size_t)(k + 2) * TT];
    float x3 = xp[(size_t)(k + 3) * TT];
#pragma unroll
    for (int j = 0; j < 8; ++j) {
      const float4 w = *(const float4*)(Win + (size_t)(n0 + j) * DD + k);
      acc[j] = fmaf(x0, w.x, fmaf(x1, w.y, fmaf(x2, w.z, fmaf(x3, w.w, acc[j]))));
    }
  }
  if (t < TT) {
#pragma unroll
    for (int j = 0; j < 8; ++j)
      wxT[((size_t)b * DD + n0 + j) * TT + t] = acc[j] + bin[n0 + j];
  }
}

// ---------------- one GEMM stage: out[b0+r][n] = sum_k in[b0+r][k]*Wt[k][n]
// R0-proven microkernel. WG: 512 thr = 8 waves. Tile 8 b-rows x 32 n-cols.
// Wave = k-eighth (128). Thread: 1 n-col, 4 b-rows. Weights 8-deep dbuf.
// Inter-stage coherence now comes from stream-ordered kernel dispatch
// (AQL acquire/release handled by the CP) -- no software barriers at all.
__device__ __forceinline__ float stage_gemm(const float* __restrict__ Wt,
                                            const float* __restrict__ inrows,
                                            float* __restrict__ in_s,
                                            float* __restrict__ red,
                                            int tid, int k0, int nn, int bg) {
  {  // stage 8 rows (32 KB) into LDS: 4 float4 per thread, coalesced
    const float4* __restrict__ s4 = (const float4*)inrows;
    float4* d4 = (float4*)in_s;
    float4 t0 = s4[tid], t1 = s4[tid + 512], t2 = s4[tid + 1024], t3 = s4[tid + 1536];
    d4[tid] = t0;
    d4[tid + 512] = t1;
    d4[tid + 1024] = t2;
    d4[tid + 1536] = t3;
  }
  __syncthreads();

  const float* wp = Wt + (size_t)k0 * DD + nn;  // lane-coalesced over n
  const float* isp = in_s + ((bg << 2) << 10) + k0;
  float acc[4];
#pragma unroll
  for (int j = 0; j < 4; ++j) acc[j] = 0.f;
  float wa[8], wb[8];
#pragma unroll
  for (int j = 0; j < 8; ++j) wa[j] = wp[j * DD];

#pragma unroll
  for (int kk = 0; kk < 128; kk += 16) {
#pragma unroll
    for (int j = 0; j < 8; ++j) wb[j] = wp[(kk + 8 + j) * DD];
#pragma unroll
    for (int rr = 0; rr < 4; ++rr) {
      const float4 a = *(const float4*)(isp + (rr << 10) + kk);  // LDS bcast/half-wave
      const float4 b = *(const float4*)(isp + (rr << 10) + kk + 4);
      acc[rr] = fmaf(a.x, wa[0], fmaf(a.y, wa[1], fmaf(a.z, wa[2], fmaf(a.w, wa[3], acc[rr]))));
      acc[rr] = fmaf(b.x, wa[4], fmaf(b.y, wa[5], fmaf(b.z, wa[6], fmaf(b.w, wa[7], acc[rr]))));
    }
#pragma unroll
    for (int j = 0; j < 8; ++j) wa[j] = wp[((kk + 16 + j) & 127) * DD];  // wrap: in-bounds
#pragma unroll
    for (int rr = 0; rr < 4; ++rr) {
      const float4 a = *(const float4*)(isp + (rr << 10) + kk + 8);
      const float4 b = *(const float4*)(isp + (rr << 10) + kk + 12);
      acc[rr] = fmaf(a.x, wb[0], fmaf(a.y, wb[1], fmaf(a.z, wb[2], fmaf(a.w, wb[3], acc[rr]))));
      acc[rr] = fmaf(b.x, wb[4], fmaf(b.y, wb[5], fmaf(b.z, wb[6], fmaf(b.w, wb[7], acc[rr]))));
    }
  }

  // cross-wave K reduction through LDS
  const int ob = ((tid >> 6) << 8) + (bg << 7) + (nn & 31);
  red[ob] = acc[0];
  red[ob + 32] = acc[1];
  red[ob + 64] = acc[2];
  red[ob + 96] = acc[3];
  __syncthreads();
  float v = 0.f;
  if (tid < 256) {
#pragma unroll
    for (int w = 0; w < 8; ++w) v += red[(w << 8) + tid];
  }
  return v;
}

// Common per-thread geometry for all stage kernels.
#define STAGE_PROLOGUE                                        \
  __shared__ float in_s[8192];                                \
  __shared__ float red[2048];                                 \
  const int tid = threadIdx.x;                                \
  const int lane = tid & 63;                                  \
  const int ntile = blockIdx.x & 31;                          \
  const int btile = blockIdx.x >> 5;                          \
  const int n0 = ntile << 5;                                  \
  const int b0 = btile << 3;                                  \
  const int nn = n0 + (lane & 31);                            \
  const int bg = lane >> 5;                                   \
  const int k0 = (tid >> 6) << 7;                             \
  const bool owner = tid < 256;                               \
  const int orow = (tid & 255) >> 5;                          \
  const int ocol = tid & 31;                                  \
  const size_t o = (size_t)(b0 + orow) * DD + (n0 + ocol);

// stage A: F1 = elu(s @ Whid^T + bh + wx[t])
__global__ void __launch_bounds__(THR, 1) kA(const float* __restrict__ WtH,
                                             const float* __restrict__ sbuf,
                                             const float* __restrict__ bh_,
                                             const float* __restrict__ wxT,
                                             float* __restrict__ F1b, int t) {
  STAGE_PROLOGUE
  float v = stage_gemm(WtH, sbuf + (size_t)b0 * DD, in_s, red, tid, k0, nn, bg);
  if (owner) F1b[o] = eluf(v + bh_[n0 + ocol] + wxT[o * TT + t]);
}

// stage B: G = elu(F1 @ W2^T + b2)
__global__ void __launch_bounds__(THR, 1) kB(const float* __restrict__ Wt2,
                                             const float* __restrict__ F1b,
                                             const float* __restrict__ b2_,
                                             float* __restrict__ Gb) {
  STAGE_PROLOGUE
  float v = stage_gemm(Wt2, F1b + (size_t)b0 * DD, in_s, red, tid, k0, nn, bg);
  if (owner) Gb[o] = eluf(v + b2_[n0 + ocol]);
}

// stage C: Fn = elu(G @ W3^T + b3); h += eta*(Fn - h - h0); write next s
__global__ void __launch_bounds__(THR, 1) kC(const float* __restrict__ Wt3,
                                             const float* __restrict__ Gb,
                                             const float* __restrict__ b3_,
                                             const float* __restrict__ etas_,
                                             float* __restrict__ h_cur,
                                             float* __restrict__ h0b,
                                             float* __restrict__ sbuf, int it) {
  STAGE_PROLOGUE
  float v = stage_gemm(Wt3, Gb + (size_t)b0 * DD, in_s, red, tid, k0, nn, bg);
  if (owner) {
    const float fn = eluf(v + b3_[n0 + ocol]);
    const float e = etas_[it];
    const float h = h_cur[o];
    const float h0 = h0b[o];
    const float hn = h + e * (fn - h - h0);
    h_cur[o] = hn;
    if (it == 4) {  // step transition: h0 <- h_t, s <- 2*h_t
      sbuf[o] = 2.f * hn;
      h0b[o] = hn;
    } else {
      sbuf[o] = hn + h0;
    }
  }
}

// output GEMM: y_t = h_t @ Wout^T + bo   (h_t lives in h0b after C(it=4))
__global__ void __launch_bounds__(THR, 1) kO(const float* __restrict__ WtO,
                                             const float* __restrict__ h0b,
                                             const float* __restrict__ bo_,
                                             float* __restrict__ outp, int t) {
  STAGE_PROLOGUE
  float v = stage_gemm(WtO, h0b + (size_t)b0 * DD, in_s, red, tid, k0, nn, bg);
  if (owner) outp[o * TT + t] = v + bo_[n0 + ocol];
}

extern "C" void kernel_launch(void* const* d_in, const int* in_sizes, int n_in,
                              void* d_out, int out_size, void* d_ws, size_t ws_size,
                              hipStream_t stream) {
  const float* x = (const float*)d_in[0];
  const float* Win = (const float*)d_in[1];
  const float* bin = (const float*)d_in[2];
  const float* Whid = (const float*)d_in[3];
  const float* bhid = (const float*)d_in[4];
  const float* W2 = (const float*)d_in[5];
  const float* b2 = (const float*)d_in[6];
  const float* W3 = (const float*)d_in[7];
  const float* b3 = (const float*)d_in[8];
  const float* Wout = (const float*)d_in[9];
  const float* bout = (const float*)d_in[10];
  const float* etas = (const float*)d_in[11];
  float* out = (float*)d_out;

  char* ws = (char*)d_ws;
  float* wxT = (float*)(ws);                   // 52.4 MB  [B][D][T]
  float* WtH = (float*)(ws + 52428800);        // 4 MB each, k-major
  float* Wt2 = (float*)(ws + 56623104);
  float* Wt3 = (float*)(ws + 60817408);
  float* WtO = (float*)(ws + 65011712);
  float* sbuf = (float*)(ws + 69206016);       // 256 KB each
  float* F1b = (float*)(ws + 69468160);
  float* Gb = (float*)(ws + 69730304);
  float* h_cur = (float*)(ws + 69992448);
  float* h0b = (float*)(ws + 70254592);

  hipMemsetAsync(sbuf, 0, 262144, stream);
  hipMemsetAsync(h_cur, 0, 262144, stream);
  hipMemsetAsync(h0b, 0, 262144, stream);

  dim3 tb(256);
  dim3 tg(32, 32);
  hipLaunchKernelGGL(transpose_k, tg, tb, 0, stream, Whid, WtH);
  hipLaunchKernelGGL(transpose_k, tg, tb, 0, stream, W2, Wt2);
  hipLaunchKernelGGL(transpose_k, tg, tb, 0, stream, W3, Wt3);
  hipLaunchKernelGGL(transpose_k, tg, tb, 0, stream, Wout, WtO);
  hipLaunchKernelGGL(wx_kernel, dim3(8192), tb, 0, stream, x, Win, bin, wxT);

  // The whole recurrence as stream-ordered dispatches (graph-captured):
  // coherence between stages is the CP's AQL acquire/release — no software
  // barriers, no fences, no spin loops.
  const dim3 sg(NWG);
  const dim3 sb(THR);
  for (int t = 0; t < TT; ++t) {
    for (int it = 0; it < 5; ++it) {
      hipLaunchKernelGGL(kA, sg, sb, 0, stream, WtH, sbuf, bhid, wxT, F1b, t);
      hipLaunchKernelGGL(kB, sg, sb, 0, stream, Wt2, F1b, b2, Gb);
      hipLaunchKernelGGL(kC, sg, sb, 0, stream, Wt3, Gb, b3, etas, h_cur, h0b, sbuf, it);
    }
    hipLaunchKernelGGL(kO, sg, sb, 0, stream, WtO, h0b, bout, out, t);
  }
}

// Round 10
// 23064.690 us; speedup vs baseline: 8.5477x; 1.0157x over previous
//
#include <hip/hip_runtime.h>
#include <cmath>

#define DD 1024
#define TT 200
#define NWG 256
#define THR 512

__device__ __forceinline__ float eluf(float x) { return x > 0.f ? x : expm1f(x); }

// ---------------- 1024x1024 transpose: dst[k][n] = src[n][k] ----------------
__global__ __launch_bounds__(256) void transpose_k(const float* __restrict__ src,
                                                   float* __restrict__ dst) {
  __shared__ float tile[32][33];
  const int bx = blockIdx.x << 5;
  const int by = blockIdx.y << 5;
  const int tx = threadIdx.x & 31;
  const int ty = threadIdx.x >> 5;
#pragma unroll
  for (int i = 0; i < 4; ++i) {
    int r = ty + (i << 3);
    tile[r][tx] = src[(size_t)(bx + r) * DD + by + tx];
  }
  __syncthreads();
#pragma unroll
  for (int i = 0; i < 4; ++i) {
    int r = ty + (i << 3);
    dst[(size_t)(by + r) * DD + bx + tx] = tile[tx][r];
  }
}

// ---------------- phase 0: wxT[b][n][t] = sum_k x[b][k][t]*Win[n][k] + bin[n]
__global__ __launch_bounds__(256) void wx_kernel(const float* __restrict__ x,
                                                 const float* __restrict__ Win,
                                                 const float* __restrict__ bin,
                                                 float* __restrict__ wxT) {
  const int gw = (blockIdx.x << 2) | (threadIdx.x >> 6);
  const int lane = threadIdx.x & 63;
  const int noct = gw & 127;
  const int tt = (gw >> 7) & 3;
  const int b = gw >> 9;
  const int n0 = noct << 3;
  const int t = (tt << 6) + lane;
  const int tl = t < TT ? t : (TT - 1);
  const float* xp = x + (size_t)b * DD * TT + tl;
  float acc[8];
#pragma unroll
  for (int j = 0; j < 8; ++j) acc[j] = 0.f;
  for (int k = 0; k < DD; k += 4) {
    float x0 = xp[(size_t)(k + 0) * TT];
    float x1 = xp[(size_t)(k + 1) * TT];
    float x2 = xp[(size_t)(k + 2) * TT];
    float x3 = xp[(size_t)(k + 3) * TT];
#pragma unroll
    for (int j = 0; j < 8; ++j) {
      const float4 w = *(const float4*)(Win + (size_t)(n0 + j) * DD + k);
      acc[j] = fmaf(x0, w.x, fmaf(x1, w.y, fmaf(x2, w.z, fmaf(x3, w.w, acc[j]))));
    }
  }
  if (t < TT) {
#pragma unroll
    for (int j = 0; j < 8; ++j)
      wxT[((size_t)b * DD + n0 + j) * TT + t] = acc[j] + bin[n0 + j];
  }
}

// ---------------- one GEMM stage: out[b0+r][n] = sum_k in[b0+r][k]*Wt[k][n]
// WG: 512 thr = 8 waves. Tile 8 b-rows x 32 n-cols. Wave = k-eighth (128).
// Weights 16-deep double-buffered (32 KB/CU in flight vs ~600-900cy MALL
// latency); first block issued BEFORE the staging barrier so its latency
// hides under activation staging. K-accumulation order identical to the
// 8-deep version -> bit-identical numerics. Inter-stage coherence comes from
// stream-ordered dispatch (CP AQL acquire/release) -- no software barriers.
__device__ __forceinline__ float stage_gemm(const float* __restrict__ Wt,
                                            const float* __restrict__ inrows,
                                            float* __restrict__ in_s,
                                            float* __restrict__ red,
                                            int tid, int k0, int nn, int bg) {
  const float* wp = Wt + (size_t)k0 * DD + nn;  // lane-coalesced over n
  float wa[16], wb[16];
  {  // stage 8 rows (32 KB) into LDS; weight block 0 issued in the shadow
    const float4* __restrict__ s4 = (const float4*)inrows;
    float4* d4 = (float4*)in_s;
    float4 t0 = s4[tid], t1 = s4[tid + 512], t2 = s4[tid + 1024], t3 = s4[tid + 1536];
#pragma unroll
    for (int j = 0; j < 16; ++j) wa[j] = wp[j * DD];  // in flight across barrier
    d4[tid] = t0;
    d4[tid + 512] = t1;
    d4[tid + 1024] = t2;
    d4[tid + 1536] = t3;
  }
  __syncthreads();

  const float* isp = in_s + ((bg << 2) << 10) + k0;
  float acc[4];
#pragma unroll
  for (int j = 0; j < 4; ++j) acc[j] = 0.f;

#pragma unroll
  for (int kk = 0; kk < 128; kk += 32) {
#pragma unroll
    for (int j = 0; j < 16; ++j) wb[j] = wp[(kk + 16 + j) * DD];
#pragma unroll
    for (int rr = 0; rr < 4; ++rr) {
      const float* ip = isp + (rr << 10) + kk;
      const float4 a = *(const float4*)(ip);       // LDS bcast/half-wave
      const float4 b = *(const float4*)(ip + 4);
      const float4 c = *(const float4*)(ip + 8);
      const float4 d = *(const float4*)(ip + 12);
      acc[rr] = fmaf(a.x, wa[0], fmaf(a.y, wa[1], fmaf(a.z, wa[2], fmaf(a.w, wa[3], acc[rr]))));
      acc[rr] = fmaf(b.x, wa[4], fmaf(b.y, wa[5], fmaf(b.z, wa[6], fmaf(b.w, wa[7], acc[rr]))));
      acc[rr] = fmaf(c.x, wa[8], fmaf(c.y, wa[9], fmaf(c.z, wa[10], fmaf(c.w, wa[11], acc[rr]))));
      acc[rr] = fmaf(d.x, wa[12], fmaf(d.y, wa[13], fmaf(d.z, wa[14], fmaf(d.w, wa[15], acc[rr]))));
    }
#pragma unroll
    for (int j = 0; j < 16; ++j) wa[j] = wp[((kk + 32 + j) & 127) * DD];  // wrap: in-bounds
#pragma unroll
    for (int rr = 0; rr < 4; ++rr) {
      const float* ip = isp + (rr << 10) + kk + 16;
      const float4 a = *(const float4*)(ip);
      const float4 b = *(const float4*)(ip + 4);
      const float4 c = *(const float4*)(ip + 8);
      const float4 d = *(const float4*)(ip + 12);
      acc[rr] = fmaf(a.x, wb[0], fmaf(a.y, wb[1], fmaf(a.z, wb[2], fmaf(a.w, wb[3], acc[rr]))));
      acc[rr] = fmaf(b.x, wb[4], fmaf(b.y, wb[5], fmaf(b.z, wb[6], fmaf(b.w, wb[7], acc[rr]))));
      acc[rr] = fmaf(c.x, wb[8], fmaf(c.y, wb[9], fmaf(c.z, wb[10], fmaf(c.w, wb[11], acc[rr]))));
      acc[rr] = fmaf(d.x, wb[12], fmaf(d.y, wb[13], fmaf(d.z, wb[14], fmaf(d.w, wb[15], acc[rr]))));
    }
  }

  // cross-wave K reduction through LDS
  const int ob = ((tid >> 6) << 8) + (bg << 7) + (nn & 31);
  red[ob] = acc[0];
  red[ob + 32] = acc[1];
  red[ob + 64] = acc[2];
  red[ob + 96] = acc[3];
  __syncthreads();
  float v = 0.f;
  if (tid < 256) {
#pragma unroll
    for (int w = 0; w < 8; ++w) v += red[(w << 8) + tid];
  }
  return v;
}

// Common per-thread geometry for all stage kernels.
#define STAGE_PROLOGUE                                        \
  __shared__ float in_s[8192];                                \
  __shared__ float red[2048];                                 \
  const int tid = threadIdx.x;                                \
  const int lane = tid & 63;                                  \
  const int ntile = blockIdx.x & 31;                          \
  const int btile = blockIdx.x >> 5;                          \
  const int n0 = ntile << 5;                                  \
  const int b0 = btile << 3;                                  \
  const int nn = n0 + (lane & 31);                            \
  const int bg = lane >> 5;                                   \
  const int k0 = (tid >> 6) << 7;                             \
  const bool owner = tid < 256;                               \
  const int orow = (tid & 255) >> 5;                          \
  const int ocol = tid & 31;                                  \
  const size_t o = (size_t)(b0 + orow) * DD + (n0 + ocol);

// stage A: F1 = elu(s @ Whid^T + bh + wx[t])
__global__ void __launch_bounds__(THR, 1) kA(const float* __restrict__ WtH,
                                             const float* __restrict__ sbuf,
                                             const float* __restrict__ bh_,
                                             const float* __restrict__ wxT,
                                             float* __restrict__ F1b, int t) {
  STAGE_PROLOGUE
  float v = stage_gemm(WtH, sbuf + (size_t)b0 * DD, in_s, red, tid, k0, nn, bg);
  if (owner) F1b[o] = eluf(v + bh_[n0 + ocol] + wxT[o * TT + t]);
}

// stage B: G = elu(F1 @ W2^T + b2)
__global__ void __launch_bounds__(THR, 1) kB(const float* __restrict__ Wt2,
                                             const float* __restrict__ F1b,
                                             const float* __restrict__ b2_,
                                             float* __restrict__ Gb) {
  STAGE_PROLOGUE
  float v = stage_gemm(Wt2, F1b + (size_t)b0 * DD, in_s, red, tid, k0, nn, bg);
  if (owner) Gb[o] = eluf(v + b2_[n0 + ocol]);
}

// stage C: Fn = elu(G @ W3^T + b3); h += eta*(Fn - h - h0); write next s.
// At it==4 additionally journals h_t into hall[t*65536 + o] (if provided) so
// the 200 output GEMMs can run as ONE deferred launch off the critical chain.
__global__ void __launch_bounds__(THR, 1) kC(const float* __restrict__ Wt3,
                                             const float* __restrict__ Gb,
                                             const float* __restrict__ b3_,
                                             const float* __restrict__ etas_,
                                             float* __restrict__ h_cur,
                                             float* __restrict__ h0b,
                                             float* __restrict__ sbuf,
                                             float* __restrict__ hall,
                                             int it, int t) {
  STAGE_PROLOGUE
  float v = stage_gemm(Wt3, Gb + (size_t)b0 * DD, in_s, red, tid, k0, nn, bg);
  if (owner) {
    const float fn = eluf(v + b3_[n0 + ocol]);
    const float e = etas_[it];
    const float h = h_cur[o];
    const float h0 = h0b[o];
    const float hn = h + e * (fn - h - h0);
    h_cur[o] = hn;
    if (it == 4) {  // step transition: h0 <- h_t, s <- 2*h_t
      sbuf[o] = 2.f * hn;
      h0b[o] = hn;
      if (hall) hall[(size_t)t * 65536 + o] = hn;  // stride = B*D = 64*1024
    } else {
      sbuf[o] = hn + h0;
    }
  }
}

// per-step output GEMM (fallback path when workspace can't hold hall)
__global__ void __launch_bounds__(THR, 1) kO(const float* __restrict__ WtO,
                                             const float* __restrict__ h0b,
                                             const float* __restrict__ bo_,
                                             float* __restrict__ outp, int t) {
  STAGE_PROLOGUE
  float v = stage_gemm(WtO, h0b + (size_t)b0 * DD, in_s, red, tid, k0, nn, bg);
  if (owner) outp[o * TT + t] = v + bo_[n0 + ocol];
}

// deferred batched output GEMM: all 200 steps in one launch, WtO L2-hot
__global__ void __launch_bounds__(THR, 1) kOall(const float* __restrict__ WtO,
                                                const float* __restrict__ hall,
                                                const float* __restrict__ bo_,
                                                float* __restrict__ outp) {
  STAGE_PROLOGUE
  const int t = blockIdx.y;
  float v = stage_gemm(WtO, hall + (size_t)t * 65536 + (size_t)b0 * DD,
                       in_s, red, tid, k0, nn, bg);
  if (owner) outp[o * TT + t] = v + bo_[n0 + ocol];
}

extern "C" void kernel_launch(void* const* d_in, const int* in_sizes, int n_in,
                              void* d_out, int out_size, void* d_ws, size_t ws_size,
                              hipStream_t stream) {
  const float* x = (const float*)d_in[0];
  const float* Win = (const float*)d_in[1];
  const float* bin = (const float*)d_in[2];
  const float* Whid = (const float*)d_in[3];
  const float* bhid = (const float*)d_in[4];
  const float* W2 = (const float*)d_in[5];
  const float* b2 = (const float*)d_in[6];
  const float* W3 = (const float*)d_in[7];
  const float* b3 = (const float*)d_in[8];
  const float* Wout = (const float*)d_in[9];
  const float* bout = (const float*)d_in[10];
  const float* etas = (const float*)d_in[11];
  float* out = (float*)d_out;

  char* ws = (char*)d_ws;
  float* wxT = (float*)(ws);                   // 52.4 MB  [B][D][T]
  float* WtH = (float*)(ws + 52428800);        // 4 MB each, k-major
  float* Wt2 = (float*)(ws + 56623104);
  float* Wt3 = (float*)(ws + 60817408);
  float* WtO = (float*)(ws + 65011712);
  float* sbuf = (float*)(ws + 69206016);       // 256 KB each
  float* F1b = (float*)(ws + 69468160);
  float* Gb = (float*)(ws + 69730304);
  float* h_cur = (float*)(ws + 69992448);
  float* h0b = (float*)(ws + 70254592);
  // optional h-journal for deferred output GEMMs: [T][B*D] = 52.4 MB
  const bool deferO = ws_size >= (70516736ull + 52428800ull);
  float* hall = deferO ? (float*)(ws + 70516736) : nullptr;

  hipMemsetAsync(sbuf, 0, 262144, stream);
  hipMemsetAsync(h_cur, 0, 262144, stream);
  hipMemsetAsync(h0b, 0, 262144, stream);

  dim3 tb(256);
  dim3 tg(32, 32);
  hipLaunchKernelGGL(transpose_k, tg, tb, 0, stream, Whid, WtH);
  hipLaunchKernelGGL(transpose_k, tg, tb, 0, stream, W2, Wt2);
  hipLaunchKernelGGL(transpose_k, tg, tb, 0, stream, W3, Wt3);
  hipLaunchKernelGGL(transpose_k, tg, tb, 0, stream, Wout, WtO);
  hipLaunchKernelGGL(wx_kernel, dim3(8192), tb, 0, stream, x, Win, bin, wxT);

  // The recurrence as stream-ordered dispatches (graph-captured). Coherence
  // between stages is the CP's AQL acquire/release. Output GEMMs are off the
  // critical chain (journaled h -> one batched launch) when workspace allows.
  const dim3 sg(NWG);
  const dim3 sb(THR);
  for (int t = 0; t < TT; ++t) {
    for (int it = 0; it < 5; ++it) {
      hipLaunchKernelGGL(kA, sg, sb, 0, stream, WtH, sbuf, bhid, wxT, F1b, t);
      hipLaunchKernelGGL(kB, sg, sb, 0, stream, Wt2, F1b, b2, Gb);
      hipLaunchKernelGGL(kC, sg, sb, 0, stream, Wt3, Gb, b3, etas, h_cur, h0b,
                         sbuf, hall, it, t);
    }
    if (!deferO)
      hipLaunchKernelGGL(kO, sg, sb, 0, stream, WtO, h0b, bout, out, t);
  }
  if (deferO)
    hipLaunchKernelGGL(kOall, dim3(NWG, TT), sb, 0, stream, WtO, hall, bout, out);
}